// Round 3
// baseline (224.266 us; speedup 1.0000x reference)
//
#include <hip/hip_runtime.h>
#include <math.h>

#define N_ 2048
#define R_ 64
#define D_ 64
#define K_ 512
#define M_ (N_*R_)      // 131072 rows
#define BM 128          // rows per argmin block (= 2 batch entries)
#define LDW 132         // padded LDS stride

// ws layout (floats): [0]=vq accumulator, [16..527]=wn (||w_k||^2), [1024..5119]=gram

// ---------------- k_pre: gram rows (blocks 0..63) + wn + zero accum (blocks 64,65)
__global__ void k_pre(const float* __restrict__ w, float* __restrict__ ws) {
    const int b = blockIdx.x, t = threadIdx.x;
    if (b < 64) {
        __shared__ float red[4][64];
        const int i = b, j = t & 63, kg = t >> 6;
        float s = 0.f;
        for (int k = kg * 128; k < kg * 128 + 128; ++k)
            s = fmaf(w[k * 64 + i], w[k * 64 + j], s);
        red[kg][j] = s;
        __syncthreads();
        if (t < 64)
            ws[1024 + i * 64 + t] = red[0][t] + red[1][t] + red[2][t] + red[3][t];
    } else {
        const int code = (b - 64) * 256 + t;   // 512 codes over blocks 64,65
        const float4* wr = (const float4*)(w + code * 64);
        float s = 0.f;
#pragma unroll
        for (int i = 0; i < 16; ++i) {
            float4 v = wr[i];
            s += v.x * v.x + v.y * v.y + v.z * v.z + v.w * v.w;
        }
        ws[16 + code] = s;
        if (b == 64 && t == 0) ws[0] = 0.f;
    }
}

// ---------------- k_argmin: scores + argmin + gather + fused vq partial
__global__ __launch_bounds__(256, 4) void k_argmin(
    const float* __restrict__ x, const float* __restrict__ w,
    float* __restrict__ ws, float* __restrict__ out)
{
    __shared__ float XT[32][LDW];          // x d-half, transposed+swizzled
    __shared__ float WT[32][LDW];          // w chunk d-half, transposed+swizzled
    __shared__ int   ridx[BM];
    __shared__ float red[2][4][64];

    const int t = threadIdx.x;
    const long base = (long)blockIdx.x * BM;
    const int tm = t >> 4, tk = t & 15;    // 16 row-groups x 16 code-groups
    const int srow = t >> 3, sc4 = t & 7;  // staging decomposition
    const float* wsn = ws + 16;

    float bestv[8]; int besti[8];
#pragma unroll
    for (int i = 0; i < 8; ++i) { bestv[i] = 3.4e38f; besti[i] = 0; }

    for (int c = 0; c < 4; ++c) {
        const int cbase = c * 128;
        float accA[8][4], accB[8][4];
#pragma unroll
        for (int i = 0; i < 8; ++i)
#pragma unroll
            for (int j = 0; j < 4; ++j) { accA[i][j] = 0.f; accB[i][j] = 0.f; }

        for (int h = 0; h < 2; ++h) {
            __syncthreads();               // previous phase's reads done
            const int sw = sc4 * 4;        // swizzle s(d) = d & 28 for this lane's d-group
#pragma unroll
            for (int i = 0; i < 4; ++i) {  // stage XT: 128 rows x 32 d
                const int row = i * 32 + srow;
                float4 v = *(const float4*)(x + (base + row) * 64 + h * 32 + sw);
                XT[sw + 0][row ^ sw] = v.x;
                XT[sw + 1][row ^ sw] = v.y;
                XT[sw + 2][row ^ sw] = v.z;
                XT[sw + 3][row ^ sw] = v.w;
            }
#pragma unroll
            for (int i = 0; i < 4; ++i) {  // stage WT: 128 codes x 32 d
                const int code = i * 32 + srow;
                float4 v = *(const float4*)(w + (long)(cbase + code) * 64 + h * 32 + sw);
                WT[sw + 0][code ^ sw] = v.x;
                WT[sw + 1][code ^ sw] = v.y;
                WT[sw + 2][code ^ sw] = v.z;
                WT[sw + 3][code ^ sw] = v.w;
            }
            __syncthreads();

#pragma unroll
            for (int dg = 0; dg < 8; ++dg) {
                const int sd = dg * 4;     // = d & 28, constant across the 4-d group
#pragma unroll
                for (int k = 0; k < 4; ++k) {
                    const int d = sd + k;
                    const float4 xa = *(const float4*)&XT[d][(tm * 8) ^ sd];
                    const float4 xb = *(const float4*)&XT[d][(tm * 8 + 4) ^ sd];
                    const float4 wa = *(const float4*)&WT[d][(tk * 4) ^ sd];
                    const float4 wb = *(const float4*)&WT[d][(64 + tk * 4) ^ sd];
                    const float xr[8]  = {xa.x, xa.y, xa.z, xa.w, xb.x, xb.y, xb.z, xb.w};
                    const float wva[4] = {wa.x, wa.y, wa.z, wa.w};
                    const float wvb[4] = {wb.x, wb.y, wb.z, wb.w};
#pragma unroll
                    for (int i = 0; i < 8; ++i)
#pragma unroll
                        for (int j = 0; j < 4; ++j) {
                            accA[i][j] = fmaf(xr[i], wva[j], accA[i][j]);
                            accB[i][j] = fmaf(xr[i], wvb[j], accB[i][j]);
                        }
                }
            }
        }

        // selection epilogue (ascending code order + strict less => lowest-index ties)
#pragma unroll
        for (int j = 0; j < 4; ++j) {
            const int cA = cbase + tk * 4 + j, cB = cA + 64;
            const float wnA = wsn[cA], wnB = wsn[cB];
#pragma unroll
            for (int i = 0; i < 8; ++i) {
                const float sA = fmaf(-2.f, accA[i][j], wnA);
                if (sA < bestv[i]) { bestv[i] = sA; besti[i] = cA; }
                const float sB = fmaf(-2.f, accB[i][j], wnB);
                if (sB < bestv[i]) { bestv[i] = sB; besti[i] = cB; }
            }
        }
    }

    // cross-lane (16 code-groups, consecutive lanes) argmin reduce, tie -> lower index
#pragma unroll
    for (int m = 1; m < 16; m <<= 1) {
#pragma unroll
        for (int i = 0; i < 8; ++i) {
            const float ov = __shfl_xor(bestv[i], m, 64);
            const int   oi = __shfl_xor(besti[i], m, 64);
            if (ov < bestv[i] || (ov == bestv[i] && oi < besti[i])) {
                bestv[i] = ov; besti[i] = oi;
            }
        }
    }
    if (tk == 0)
#pragma unroll
        for (int i = 0; i < 8; ++i) ridx[tm * 8 + i] = besti[i];
    __syncthreads();

    // gather codebook rows -> q_sg, q; fused vq partial (block = 2 batch entries)
    float* q_sg = out + 5;
    float* q    = out + 5 + (long)M_ * 64;
    float* fidx = out + 5 + 2L * M_ * 64;
    const int d = t & 63, tg = t >> 6;
    float vq0 = 0.f, vq1 = 0.f;
#pragma unroll
    for (int i = 0; i < 16; ++i) {         // rows r < 64 (first batch entry)
        const int r = i * 4 + tg;
        const float wv = w[(long)ridx[r] * 64 + d];
        const float xv = x[(base + r) * 64 + d];
        const long off = base * 64 + (long)r * 64 + d;
        q_sg[off] = wv; q[off] = wv;
        const float df = wv - xv, p = df * df;
        vq0 = fmaf(p, p, vq0);
    }
#pragma unroll
    for (int i = 16; i < 32; ++i) {        // rows r >= 64 (second batch entry)
        const int r = i * 4 + tg;
        const float wv = w[(long)ridx[r] * 64 + d];
        const float xv = x[(base + r) * 64 + d];
        const long off = base * 64 + (long)r * 64 + d;
        q_sg[off] = wv; q[off] = wv;
        const float df = wv - xv, p = df * df;
        vq1 = fmaf(p, p, vq1);
    }
    red[0][tg][d] = vq0; red[1][tg][d] = vq1;
    if (t < BM) fidx[base + t] = (float)ridx[t];
    __syncthreads();
    if (t < 128) {                          // wave 0 -> n0, wave 1 -> n1
        const int n = t >> 6, dd = t & 63;
        float v = sqrtf(red[n][0][dd] + red[n][1][dd] + red[n][2][dd] + red[n][3][dd]);
#pragma unroll
        for (int m = 1; m < 64; m <<= 1) v += __shfl_xor(v, m, 64);
        if (dd == 0) atomicAdd(ws + 0, v);
    }
}

// ---------------- k_final: orth from gram, rank via Gaussian elimination, losses
__global__ void k_final(const float* __restrict__ ws, float* __restrict__ out)
{
    __shared__ float g[64][65];
    __shared__ float osum[4];
    __shared__ float tol;
    const int t = threadIdx.x;
    float oacc = 0.f;
    for (int i = t; i < 4096; i += 256) {
        const int r = i >> 6, cl = i & 63;
        const float gv = ws[1024 + i];
        g[r][cl] = gv;
        const float p = gv - (r == cl ? 1.f : 0.f);
        oacc = fmaf(p, p, oacc);
    }
#pragma unroll
    for (int m = 1; m < 64; m <<= 1) oacc += __shfl_xor(oacc, m, 64);
    if ((t & 63) == 0) osum[t >> 6] = oacc;
    __syncthreads();

    if (t == 0) {
        float maxd = 0.f;
        for (int i = 0; i < 64; ++i) maxd = fmaxf(maxd, fabsf(g[i][i]));
        tol = maxd * 1e-7f + 1e-30f;
    }
    __syncthreads();

    int rank = 0;
    const int j = t & 63, rq = t >> 6;
    for (int s = 0; s < 64; ++s) {
        const float p = g[s][s];
        const bool ok = fabsf(p) > tol;
        if (ok) {
            rank++;
            if (j > s) {                    // only columns > s: no race on column s
                const float rp = 1.f / p;
                const float gsj = g[s][j];
                for (int r = s + 1 + rq; r < 64; r += 4)
                    g[r][j] = fmaf(-(g[r][s] * rp), gsj, g[r][j]);
            }
        }
        __syncthreads();
    }

    if (t == 0) {
        const float vq = ws[0] / (float)(N_ * D_);
        const float orth = sqrtf(osum[0] + osum[1] + osum[2] + osum[3]);
        out[0] = 1.5f * vq;                 // 1.0*vq + 0.5*commit(=vq) + 0.0*orth
        out[1] = vq;
        out[2] = vq;
        out[3] = orth;
        out[4] = (float)rank;
    }
}

// ---------------- launcher
extern "C" void kernel_launch(void* const* d_in, const int* in_sizes, int n_in,
                              void* d_out, int out_size, void* d_ws, size_t ws_size,
                              hipStream_t stream) {
    const float* x = (const float*)d_in[0];   // soft_fillers [N,R,D]
    const float* w = (const float*)d_in[1];   // weight [K,D]
    float* out = (float*)d_out;
    float* ws  = (float*)d_ws;

    hipLaunchKernelGGL(k_pre,    dim3(66),    dim3(256), 0, stream, w, ws);
    hipLaunchKernelGGL(k_argmin, dim3(M_/BM), dim3(256), 0, stream, x, w, ws, out);
    hipLaunchKernelGGL(k_final,  dim3(1),     dim3(256), 0, stream, ws, out);
}